// Round 1
// baseline (145.331 us; speedup 1.0000x reference)
//
#include <hip/hip_runtime.h>
#include <hip/hip_bf16.h>

// Fused: qp=QWq^T+bq etc, then O = Qp (Kp^T Vp) (no softmax -> associativity),
// out[b,c,h,w] = O[w][c] + q[b,c,h,w].  One block per (b,h), bf16 MFMA.

typedef __bf16 bf16x8 __attribute__((ext_vector_type(8)));
typedef float  f32x4  __attribute__((ext_vector_type(4)));

#define LDP 68    // pixel-major row stride (bf16 elems): 136B rows, 8B-aligned
#define LDX 132   // channel-major row stride: 264B rows, 8B-aligned

__device__ __forceinline__ unsigned short f2bf(float x) {
  __hip_bfloat16 h = __float2bfloat16(x);           // RNE
  return __builtin_bit_cast(unsigned short, h);
}
__device__ __forceinline__ float bf2f(unsigned short u) {
  unsigned int t = ((unsigned int)u) << 16;
  return __builtin_bit_cast(float, t);
}
__device__ __forceinline__ unsigned int pack2(float a, float b) {
  return (unsigned int)f2bf(a) | ((unsigned int)f2bf(b) << 16);
}
// load 8 contiguous bf16 (8B-aligned) as an MFMA fragment
__device__ __forceinline__ bf16x8 ld8(const unsigned short* p) {
  uint2 lo = *reinterpret_cast<const uint2*>(p);
  uint2 hi = *reinterpret_cast<const uint2*>(p + 4);
  uint4 t;
  t.x = lo.x; t.y = lo.y; t.z = hi.x; t.w = hi.y;
  return __builtin_bit_cast(bf16x8, t);
}

__global__ __launch_bounds__(512, 1)
void fused_mha(const float* __restrict__ q, const float* __restrict__ k,
               const float* __restrict__ v,
               const float* __restrict__ wq, const float* __restrict__ bq,
               const float* __restrict__ wk, const float* __restrict__ bk,
               const float* __restrict__ wv, const float* __restrict__ bv,
               float* __restrict__ out)
{
  __shared__ unsigned short sQ [128*LDP];   // q  pixel-major [w][c] bf16
  __shared__ unsigned short sK [128*LDP];
  __shared__ unsigned short sV [128*LDP];
  __shared__ unsigned short sQP[128*LDP];   // Qp pixel-major [w][o]
  __shared__ unsigned short sKPt[64*LDX];   // Kp^T channel-major [o][x]
  __shared__ unsigned short sVPt[64*LDX];   // Vp^T channel-major [o][x]
  __shared__ unsigned short sTt[64*LDP];    // Tt[c][d] = T[d][c] = (Kp^T Vp)[d][c]
  __shared__ unsigned short sW[3][64*LDP];  // Wq,Wk,Wv natural [o][c]
  __shared__ float sB[3][64];

  const int tid  = threadIdx.x;
  const int lane = tid & 63;
  const int ww   = tid >> 6;     // wave 0..7
  const int l15  = lane & 15;
  const int g    = lane >> 4;    // 0..3

  const int bh = blockIdx.x;
  const int bi = bh >> 7;
  const int hi = bh & 127;
  const size_t CS   = 128*128;                       // channel stride
  const size_t base = (size_t)bi * (64*CS) + (size_t)hi * 128;

  // ---------------- phase 0: stage weights, biases, inputs ----------------
  {
    const int wr = tid >> 6;     // 0..7
    const int c  = tid & 63;
    #pragma unroll
    for (int r = 0; r < 8; ++r) {
      int o = r*8 + wr;
      sW[0][o*LDP + c] = f2bf(wq[o*64 + c]);
      sW[1][o*LDP + c] = f2bf(wk[o*64 + c]);
      sW[2][o*LDP + c] = f2bf(wv[o*64 + c]);
    }
    if (tid < 64) {
      sB[0][tid] = bq[tid];
      sB[1][tid] = bk[tid];
      sB[2][tid] = bv[tid];
    }
    const int wp = tid & 127;            // w pixel
    const int cp = (tid >> 7) * 2;       // 0,2,4,6
    #pragma unroll
    for (int it = 0; it < 8; ++it) {
      int c0 = it*8 + cp;
      size_t a0 = base + (size_t)c0 * CS + wp;
      *reinterpret_cast<unsigned int*>(&sQ[wp*LDP + c0]) = pack2(q[a0], q[a0 + CS]);
      *reinterpret_cast<unsigned int*>(&sK[wp*LDP + c0]) = pack2(k[a0], k[a0 + CS]);
      *reinterpret_cast<unsigned int*>(&sV[wp*LDP + c0]) = pack2(v[a0], v[a0 + CS]);
    }
  }
  __syncthreads();

  // ---------------- phase 1: projections ----------------
  // (a) Qp[w][o] = sum_c Q[w][c] Wq[o][c] + bq[o]  (wave ww -> row-tile ww)
  {
    f32x4 zero = {0.f,0.f,0.f,0.f};
    f32x4 acc[4] = {zero, zero, zero, zero};
    #pragma unroll
    for (int ks = 0; ks < 2; ++ks) {
      bf16x8 a = ld8(&sQ[(16*ww + l15)*LDP + 32*ks + 8*g]);
      #pragma unroll
      for (int ct = 0; ct < 4; ++ct) {
        bf16x8 b = ld8(&sW[0][(16*ct + l15)*LDP + 32*ks + 8*g]);
        acc[ct] = __builtin_amdgcn_mfma_f32_16x16x32_bf16(a, b, acc[ct], 0, 0, 0);
      }
    }
    #pragma unroll
    for (int ct = 0; ct < 4; ++ct) {
      float bias = sB[0][16*ct + l15];
      #pragma unroll
      for (int r = 0; r < 4; ++r)
        sQP[(16*ww + 4*g + r)*LDP + 16*ct + l15] = f2bf(acc[ct][r] + bias);
    }
  }
  // (b) Kp^T[o][x] = sum_c Wk[o][c] K[x][c] + bk[o]; (c) same for V.
  // wave ww: row-tile rt = ww&3 (o), col-tiles cb..cb+3 (x)
  {
    const int rt = ww & 3;
    const int cb = (ww >> 2) * 4;
    f32x4 zero = {0.f,0.f,0.f,0.f};
    f32x4 acck[4] = {zero, zero, zero, zero};
    f32x4 accv[4] = {zero, zero, zero, zero};
    #pragma unroll
    for (int ks = 0; ks < 2; ++ks) {
      bf16x8 ak = ld8(&sW[1][(16*rt + l15)*LDP + 32*ks + 8*g]);
      bf16x8 av = ld8(&sW[2][(16*rt + l15)*LDP + 32*ks + 8*g]);
      #pragma unroll
      for (int cc = 0; cc < 4; ++cc) {
        bf16x8 bk8 = ld8(&sK[(16*(cb+cc) + l15)*LDP + 32*ks + 8*g]);
        bf16x8 bv8 = ld8(&sV[(16*(cb+cc) + l15)*LDP + 32*ks + 8*g]);
        acck[cc] = __builtin_amdgcn_mfma_f32_16x16x32_bf16(ak, bk8, acck[cc], 0, 0, 0);
        accv[cc] = __builtin_amdgcn_mfma_f32_16x16x32_bf16(av, bv8, accv[cc], 0, 0, 0);
      }
    }
    #pragma unroll
    for (int cc = 0; cc < 4; ++cc) {
      int x = 16*(cb+cc) + l15;
      #pragma unroll
      for (int r = 0; r < 4; ++r) {
        int o = 16*rt + 4*g + r;
        sKPt[o*LDX + x] = f2bf(acck[cc][r] + sB[1][o]);
        sVPt[o*LDX + x] = f2bf(accv[cc][r] + sB[2][o]);
      }
    }
  }
  __syncthreads();

  // ---------------- phase 2: Tt[c][d] = sum_x Vp^T[c][x] * Kp^T[d][x] ----------------
  // (= T[d][c] with T = Kp^T Vp).  16 tiles of 16x16, 2 per wave, K=128 (4 k-slices)
  {
    const int rt = ww >> 1;
    const int cb = (ww & 1) * 2;
    f32x4 zero = {0.f,0.f,0.f,0.f};
    f32x4 acc[2] = {zero, zero};
    #pragma unroll
    for (int ks = 0; ks < 4; ++ks) {
      bf16x8 a = ld8(&sVPt[(16*rt + l15)*LDX + 32*ks + 8*g]);
      #pragma unroll
      for (int cc = 0; cc < 2; ++cc) {
        bf16x8 b = ld8(&sKPt[(16*(cb+cc) + l15)*LDX + 32*ks + 8*g]);
        acc[cc] = __builtin_amdgcn_mfma_f32_16x16x32_bf16(a, b, acc[cc], 0, 0, 0);
      }
    }
    #pragma unroll
    for (int cc = 0; cc < 2; ++cc) {
      int d = 16*(cb+cc) + l15;
      #pragma unroll
      for (int r = 0; r < 4; ++r)
        sTt[(16*rt + 4*g + r)*LDP + d] = f2bf(acc[cc][r]);
    }
  }
  __syncthreads();

  // ---------------- phase 3: O[w][c] = sum_d Qp[w][d] * Tt[c][d]; out = O + q ----------------
  {
    f32x4 zero = {0.f,0.f,0.f,0.f};
    f32x4 acc[4] = {zero, zero, zero, zero};
    #pragma unroll
    for (int ks = 0; ks < 2; ++ks) {
      bf16x8 a = ld8(&sQP[(16*ww + l15)*LDP + 32*ks + 8*g]);
      #pragma unroll
      for (int ct = 0; ct < 4; ++ct) {
        bf16x8 b = ld8(&sTt[(16*ct + l15)*LDP + 32*ks + 8*g]);
        acc[ct] = __builtin_amdgcn_mfma_f32_16x16x32_bf16(a, b, acc[ct], 0, 0, 0);
      }
    }
    #pragma unroll
    for (int ct = 0; ct < 4; ++ct) {
      int c  = 16*ct + l15;
      int w0 = 16*ww + 4*g;
      float4 o4;
      o4.x = acc[ct][0] + bf2f(sQ[(w0+0)*LDP + c]);
      o4.y = acc[ct][1] + bf2f(sQ[(w0+1)*LDP + c]);
      o4.z = acc[ct][2] + bf2f(sQ[(w0+2)*LDP + c]);
      o4.w = acc[ct][3] + bf2f(sQ[(w0+3)*LDP + c]);
      *reinterpret_cast<float4*>(out + base + (size_t)c * CS + w0) = o4;
    }
  }
}

extern "C" void kernel_launch(void* const* d_in, const int* in_sizes, int n_in,
                              void* d_out, int out_size, void* d_ws, size_t ws_size,
                              hipStream_t stream) {
  (void)in_sizes; (void)n_in; (void)d_ws; (void)ws_size; (void)out_size;
  const float* q  = (const float*)d_in[0];
  const float* k  = (const float*)d_in[1];
  const float* v  = (const float*)d_in[2];
  const float* wq = (const float*)d_in[3];
  const float* bq = (const float*)d_in[4];
  const float* wk = (const float*)d_in[5];
  const float* bk = (const float*)d_in[6];
  const float* wv = (const float*)d_in[7];
  const float* bv = (const float*)d_in[8];
  float* out = (float*)d_out;
  fused_mha<<<dim3(32*128), dim3(512), 0, stream>>>(q, k, v, wq, bq, wk, bk, wv, bv, out);
}

// Round 2
// 112.637 us; speedup vs baseline: 1.2903x; 1.2903x over previous
//
#include <hip/hip_runtime.h>
#include <hip/hip_bf16.h>

// Fused: qp=QWq^T+bq etc, then O = Qp (Kp^T Vp) (no softmax -> associativity),
// out[b,c,h,w] = O[w][c] + q[b,c,h,w].  One block per (b,h), bf16 MFMA.
// Round 2: LDS <= 78 KB via aliasing (2 blocks/CU), Wk/Wv in register
// fragments, float4 staging loads, q prefetch (async-split staging).

typedef __bf16 bf16x8 __attribute__((ext_vector_type(8)));
typedef float  f32x4  __attribute__((ext_vector_type(4)));

#define LDP 68    // pixel-major row stride (bf16 elems): 136B rows, 8B-aligned
#define LDX 132   // channel-major row stride: 264B rows, 8B-aligned

// LDS region offsets (in ushort units)
#define OF_A 0        // sK[128][68]  -> later sTt[64][68]
#define OF_B 8704     // sV[128][68]  -> later sQ[128][68]
#define OF_C 17408    // sKPt[64][132]-> later sQP[128][68] (spills 256 into D)
#define OF_D 25856    // sVPt[64][132]
#define OF_W 34304    // sWq[64][68]
#define OF_SB 38656   // float sB[192]: [0:64)=bq [64:128)=bk [128:192)=bv
#define LDS_USHORTS (38656 + 384)

__device__ __forceinline__ unsigned short f2bf(float x) {
  __hip_bfloat16 h = __float2bfloat16(x);           // RNE
  return __builtin_bit_cast(unsigned short, h);
}
__device__ __forceinline__ float bf2f(unsigned short u) {
  unsigned int t = ((unsigned int)u) << 16;
  return __builtin_bit_cast(float, t);
}
__device__ __forceinline__ unsigned int pack2(float a, float b) {
  return (unsigned int)f2bf(a) | ((unsigned int)f2bf(b) << 16);
}
__device__ __forceinline__ bf16x8 cvt8(float4 a, float4 b) {
  union { unsigned int u[4]; bf16x8 v; } r;
  r.u[0] = pack2(a.x, a.y); r.u[1] = pack2(a.z, a.w);
  r.u[2] = pack2(b.x, b.y); r.u[3] = pack2(b.z, b.w);
  return r.v;
}
// load 8 contiguous bf16 (8B-aligned) as an MFMA fragment
__device__ __forceinline__ bf16x8 ld8(const unsigned short* p) {
  uint2 lo = *reinterpret_cast<const uint2*>(p);
  uint2 hi = *reinterpret_cast<const uint2*>(p + 4);
  uint4 t;
  t.x = lo.x; t.y = lo.y; t.z = hi.x; t.w = hi.y;
  return __builtin_bit_cast(bf16x8, t);
}

__global__ __launch_bounds__(512, 4)
void fused_mha(const float* __restrict__ q, const float* __restrict__ k,
               const float* __restrict__ v,
               const float* __restrict__ wq, const float* __restrict__ bq,
               const float* __restrict__ wk, const float* __restrict__ bk,
               const float* __restrict__ wv, const float* __restrict__ bv,
               float* __restrict__ out)
{
  __shared__ __align__(16) unsigned short lds[LDS_USHORTS];
  unsigned short* sK   = lds + OF_A;   // [128][LDP] pixel-major bf16
  unsigned short* sV   = lds + OF_B;
  unsigned short* sKPt = lds + OF_C;   // [64][LDX] channel-major
  unsigned short* sVPt = lds + OF_D;
  unsigned short* sWq  = lds + OF_W;   // [64][LDP] natural [o][c]
  unsigned short* sTt  = lds + OF_A;   // [64][LDP]  (aliases dead sK)
  unsigned short* sQ   = lds + OF_B;   // [128][LDP] (aliases dead sV)
  unsigned short* sQP  = lds + OF_C;   // [128][LDP] (aliases dead sKPt+)
  float* sB = (float*)(lds + OF_SB);

  const int tid  = threadIdx.x;
  const int lane = tid & 63;
  const int ww   = tid >> 6;     // wave 0..7
  const int l15  = lane & 15;
  const int g    = lane >> 4;    // 0..3

  const int bh = blockIdx.x;
  const int bi = bh >> 7;
  const int hi = bh & 127;
  const size_t CS   = 128*128;
  const size_t base = (size_t)bi * (64*CS) + (size_t)hi * 128;

  // staging thread mapping: 4 consecutive w, 2 channels, 2 units
  const int sw0 = 4*(tid & 31);
  const int scA = 2*((tid >> 5) & 15);

  // ---------------- phase 0: stage K,V,Wq,biases; prefetch q + W-frags ----
  // Wk/Wv fragment loads (for P1): wave handles o-rows [16*rt, 16*rt+16)
  const int rt = ww & 3;
  const int cb = (ww >> 2) * 4;
  bf16x8 wkf[2], wvf[2];
  #pragma unroll
  for (int ks = 0; ks < 2; ++ks) {
    const float* pk = wk + (16*rt + l15)*64 + 8*g + 32*ks;
    const float* pv = wv + (16*rt + l15)*64 + 8*g + 32*ks;
    wkf[ks] = cvt8(*(const float4*)pk, *(const float4*)(pk+4));
    wvf[ks] = cvt8(*(const float4*)pv, *(const float4*)(pv+4));
  }
  // q prefetch into regs (LDS-written in phase 2 when sV region dies)
  float4 qreg[4];
  #pragma unroll
  for (int u = 0; u < 2; ++u) {
    int c = scA + 32*u;
    qreg[2*u+0] = *(const float4*)(q + base + (size_t)c    *CS + sw0);
    qreg[2*u+1] = *(const float4*)(q + base + (size_t)(c+1)*CS + sw0);
  }
  // stage K, V (transpose to pixel-major bf16)
  #pragma unroll
  for (int u = 0; u < 2; ++u) {
    int c = scA + 32*u;
    float4 ka = *(const float4*)(k + base + (size_t)c    *CS + sw0);
    float4 kb = *(const float4*)(k + base + (size_t)(c+1)*CS + sw0);
    float4 va = *(const float4*)(v + base + (size_t)c    *CS + sw0);
    float4 vb = *(const float4*)(v + base + (size_t)(c+1)*CS + sw0);
    const float* kaf = (const float*)&ka; const float* kbf = (const float*)&kb;
    const float* vaf = (const float*)&va; const float* vbf = (const float*)&vb;
    #pragma unroll
    for (int j = 0; j < 4; ++j) {
      *(unsigned int*)&sK[(sw0+j)*LDP + c] = pack2(kaf[j], kbf[j]);
      *(unsigned int*)&sV[(sw0+j)*LDP + c] = pack2(vaf[j], vbf[j]);
    }
  }
  // stage Wq [o][c] bf16
  {
    const int o  = tid >> 3;
    const int c0 = (tid & 7) * 8;
    float4 a = *(const float4*)(wq + o*64 + c0);
    float4 b = *(const float4*)(wq + o*64 + c0 + 4);
    unsigned short* p = &sWq[o*LDP + c0];
    ((uint2*)p)[0] = make_uint2(pack2(a.x,a.y), pack2(a.z,a.w));
    ((uint2*)p)[1] = make_uint2(pack2(b.x,b.y), pack2(b.z,b.w));
  }
  if (tid < 64)        sB[tid]       = bq[tid];
  else if (tid < 128)  sB[tid]       = bk[tid-64];
  else if (tid < 192)  sB[tid]       = bv[tid-128];
  __syncthreads();

  // ---------------- phase 1: Kp^T[o][x], Vp^T[o][x] ----------------------
  {
    f32x4 z = {0.f,0.f,0.f,0.f};
    f32x4 acck[4] = {z,z,z,z}, accv[4] = {z,z,z,z};
    #pragma unroll
    for (int ks = 0; ks < 2; ++ks) {
      #pragma unroll
      for (int cc = 0; cc < 4; ++cc) {
        bf16x8 bk8 = ld8(&sK[(16*(cb+cc) + l15)*LDP + 32*ks + 8*g]);
        bf16x8 bv8 = ld8(&sV[(16*(cb+cc) + l15)*LDP + 32*ks + 8*g]);
        acck[cc] = __builtin_amdgcn_mfma_f32_16x16x32_bf16(wkf[ks], bk8, acck[cc], 0, 0, 0);
        accv[cc] = __builtin_amdgcn_mfma_f32_16x16x32_bf16(wvf[ks], bv8, accv[cc], 0, 0, 0);
      }
    }
    #pragma unroll
    for (int cc = 0; cc < 4; ++cc) {
      int x = 16*(cb+cc) + l15;
      #pragma unroll
      for (int r = 0; r < 4; ++r) {
        int o = 16*rt + 4*g + r;
        sKPt[o*LDX + x] = f2bf(acck[cc][r] + sB[64 + o]);
        sVPt[o*LDX + x] = f2bf(accv[cc][r] + sB[128 + o]);
      }
    }
  }
  __syncthreads();

  // ---------------- phase 2: Tt[c][d] = sum_x Vp^T[c][x] Kp^T[d][x];
  //                  also drain q regs -> sQ (sV region is dead) ----------
  {
    const int rt2 = ww >> 1;
    const int cb2 = (ww & 1) * 2;
    f32x4 z = {0.f,0.f,0.f,0.f};
    f32x4 acc[2] = {z,z};
    #pragma unroll
    for (int ks = 0; ks < 4; ++ks) {
      bf16x8 a = ld8(&sVPt[(16*rt2 + l15)*LDX + 32*ks + 8*g]);
      #pragma unroll
      for (int cc = 0; cc < 2; ++cc) {
        bf16x8 b = ld8(&sKPt[(16*(cb2+cc) + l15)*LDX + 32*ks + 8*g]);
        acc[cc] = __builtin_amdgcn_mfma_f32_16x16x32_bf16(a, b, acc[cc], 0, 0, 0);
      }
    }
    #pragma unroll
    for (int u = 0; u < 2; ++u) {
      int c = scA + 32*u;
      const float* qa = (const float*)&qreg[2*u];
      const float* qb = (const float*)&qreg[2*u+1];
      #pragma unroll
      for (int j = 0; j < 4; ++j)
        *(unsigned int*)&sQ[(sw0+j)*LDP + c] = pack2(qa[j], qb[j]);
    }
    #pragma unroll
    for (int cc = 0; cc < 2; ++cc) {
      int d = 16*(cb2+cc) + l15;
      #pragma unroll
      for (int r = 0; r < 4; ++r)
        sTt[(16*rt2 + 4*g + r)*LDP + d] = f2bf(acc[cc][r]);
    }
  }
  __syncthreads();

  // ---------------- phase 3: Qp[w][o] -> sQP (sKPt/sVPt region dead) -----
  {
    f32x4 z = {0.f,0.f,0.f,0.f};
    f32x4 acc[4] = {z,z,z,z};
    #pragma unroll
    for (int ks = 0; ks < 2; ++ks) {
      bf16x8 a = ld8(&sQ[(16*ww + l15)*LDP + 32*ks + 8*g]);
      #pragma unroll
      for (int ct = 0; ct < 4; ++ct) {
        bf16x8 b = ld8(&sWq[(16*ct + l15)*LDP + 32*ks + 8*g]);
        acc[ct] = __builtin_amdgcn_mfma_f32_16x16x32_bf16(a, b, acc[ct], 0, 0, 0);
      }
    }
    #pragma unroll
    for (int ct = 0; ct < 4; ++ct) {
      float bias = sB[16*ct + l15];
      #pragma unroll
      for (int r = 0; r < 4; ++r)
        sQP[(16*ww + 4*g + r)*LDP + 16*ct + l15] = f2bf(acc[ct][r] + bias);
    }
  }
  __syncthreads();

  // ---------------- phase 4: O[w][c] = Qp·Tt^T; out = O^T + q ------------
  {
    f32x4 z = {0.f,0.f,0.f,0.f};
    f32x4 acc[4] = {z,z,z,z};
    #pragma unroll
    for (int ks = 0; ks < 2; ++ks) {
      bf16x8 a = ld8(&sQP[(16*ww + l15)*LDP + 32*ks + 8*g]);
      #pragma unroll
      for (int ct = 0; ct < 4; ++ct) {
        bf16x8 b = ld8(&sTt[(16*ct + l15)*LDP + 32*ks + 8*g]);
        acc[ct] = __builtin_amdgcn_mfma_f32_16x16x32_bf16(a, b, acc[ct], 0, 0, 0);
      }
    }
    #pragma unroll
    for (int ct = 0; ct < 4; ++ct) {
      int c  = 16*ct + l15;
      int w0 = 16*ww + 4*g;
      float4 o4;
      o4.x = acc[ct][0] + bf2f(sQ[(w0+0)*LDP + c]);
      o4.y = acc[ct][1] + bf2f(sQ[(w0+1)*LDP + c]);
      o4.z = acc[ct][2] + bf2f(sQ[(w0+2)*LDP + c]);
      o4.w = acc[ct][3] + bf2f(sQ[(w0+3)*LDP + c]);
      *reinterpret_cast<float4*>(out + base + (size_t)c * CS + w0) = o4;
    }
  }
}

extern "C" void kernel_launch(void* const* d_in, const int* in_sizes, int n_in,
                              void* d_out, int out_size, void* d_ws, size_t ws_size,
                              hipStream_t stream) {
  (void)in_sizes; (void)n_in; (void)d_ws; (void)ws_size; (void)out_size;
  const float* q  = (const float*)d_in[0];
  const float* k  = (const float*)d_in[1];
  const float* v  = (const float*)d_in[2];
  const float* wq = (const float*)d_in[3];
  const float* bq = (const float*)d_in[4];
  const float* wk = (const float*)d_in[5];
  const float* bk = (const float*)d_in[6];
  const float* wv = (const float*)d_in[7];
  const float* bv = (const float*)d_in[8];
  float* out = (float*)d_out;
  fused_mha<<<dim3(32*128), dim3(512), 0, stream>>>(q, k, v, wq, bq, wk, bk, wv, bv, out);
}